// Round 6
// baseline (372.610 us; speedup 1.0000x reference)
//
#include <hip/hip_runtime.h>
#include <math.h>

#define BB 64
#define TT 256
#define KK 32
#define VV 32
#define CH 32                    // chunk rows per block
#define PH 32                    // steps per phase
#define ROWS (CH + PH)           // 64 rows covered per block
#define NPHASE ((TT + KK) / PH)  // 9 phases * 32 = 288 steps
#define BPB (TT / CH)            // 8 chunks per batch
#define NW (ROWS / 16)           // 4 waves per block

// workspace layout (floats)
#define RW_OFF    0                       // K*K
#define WOP_OFF   1024                    // 37*K
#define ATOM_OFF  2240                    // B*T*K
#define STATE_OFF (ATOM_OFF + BB*TT*KK)   // B*T*K (halo handoff rows only)
#define FLAG_OFF  (STATE_OFF + BB*TT*KK)  // BB*BPB ints

typedef __attribute__((ext_vector_type(8))) short short8;
typedef __attribute__((ext_vector_type(4))) float floatx4;

__device__ __forceinline__ float myrelu(float z) {
    // 0.01*z + 0.99*clamp(z,0,1)
    return fmaf(0.01f, z, 0.99f * __builtin_amdgcn_fmed3f(z, 0.f, 1.f));
}
__device__ __forceinline__ ushort f2bf(float f) {
    union { float f; unsigned int u; } v; v.f = f;
    unsigned int r = v.u + 0x7fffu + ((v.u >> 16) & 1u);
    return (ushort)(r >> 16);
}
__device__ __forceinline__ float dpp_shl1(float v) {
    // lane n <- lane n+1 within each 16-lane row; top lane of row -> 0
    return __int_as_float(__builtin_amdgcn_update_dpp(
        0, __float_as_int(v), 0x101 /*row_shl:1*/, 0xF, 0xF, true));
}

// --- softmaxes of w_op (32 x 37) and w_right (32 x 33) ---
__global__ void prep_kernel(const float* __restrict__ w_right,
                            const float* __restrict__ w_op,
                            float* __restrict__ ws) {
    int tid = threadIdx.x;
    float* rw  = ws + RW_OFF;   // rw[k*K + j] = right_w[k][j] = softmax(w_right)[j][k]
    float* wop = ws + WOP_OFF;  // wop[i*K + k] = sm_op[k][i]
    if (tid < KK) {
        float v[37];
        float m = -1e30f;
        #pragma unroll
        for (int i = 0; i < 37; ++i) { v[i] = w_op[tid * 37 + i]; m = fmaxf(m, v[i]); }
        float s = 0.f;
        #pragma unroll
        for (int i = 0; i < 37; ++i) { v[i] = expf(v[i] - m); s += v[i]; }
        float inv = 1.f / s;
        #pragma unroll
        for (int i = 0; i < 37; ++i) wop[i * KK + tid] = v[i] * inv;
    } else if (tid < 2 * KK) {
        int r = tid - KK;
        float v[KK + 1];
        float m = -1e30f;
        #pragma unroll
        for (int i = 0; i <= KK; ++i) { v[i] = w_right[r * (KK + 1) + i]; m = fmaxf(m, v[i]); }
        float s = 0.f;
        #pragma unroll
        for (int i = 0; i <= KK; ++i) { v[i] = expf(v[i] - m); s += v[i]; }
        float inv = 1.f / s;
        #pragma unroll
        for (int c = 0; c < KK; ++c) rw[c * KK + r] = v[c] * inv;
    }
}

// --- atom_x = x @ atom_w ; zero the handshake flags ---
__global__ void atomx_kernel(const float* __restrict__ x, float* __restrict__ ws) {
    const float* aw = ws + WOP_OFF + 5 * KK;
    float* atom = ws + ATOM_OFF;
    int tid = threadIdx.x;
    if (blockIdx.x < 2) ((int*)(ws + FLAG_OFF))[blockIdx.x * 256 + tid] = 0;
    int k  = tid & (KK - 1);
    int bt = blockIdx.x * 8 + (tid >> 5);
    const float* xrow = x + bt * VV;
    float acc = 0.f;
    #pragma unroll
    for (int v = 0; v < VV; ++v) acc = fmaf(xrow[v], aw[v * KK + k], acc);
    atom[bt * KK + k] = acc;
}

// --- all 288 steps in one cooperative kernel; neighbor-flag phase handoff ---
__global__ __launch_bounds__(256, 2)
void phase_all_kernel(float* __restrict__ ws, float* __restrict__ out) {
    __shared__ float brow[2][NW + 1][36];   // tile-boundary rows, dbuf
    __shared__ float dummy[64][8];          // sink for branchless brow writes

    const float* rw   = ws + RW_OFF;
    const float* wop  = ws + WOP_OFF;
    const float* atom = ws + ATOM_OFF;
    float*      state = ws + STATE_OFF;
    int*        flags = (int*)(ws + FLAG_OFF);

    int tid  = threadIdx.x;
    int lane = tid & 63;
    int rt   = tid >> 6;        // wave = row-tile 0..3
    int lr   = lane & 15;
    int hi   = lane >> 4;
    int b  = blockIdx.x / BPB;
    int c  = blockIdx.x % BPB;
    int lo = c * CH;
    int t0 = lo + rt * 16 + lr;            // this lane's global row
    bool active = (lo + rt * 16) < TT;
    bool l15 = (lr == 15);
    bool h3  = (hi == 3);

    for (int i = tid; i < 2 * (NW + 1) * 36; i += 256)
        (&brow[0][0][0])[i] = 0.f;

    float* gs = state + (size_t)b * TT * KK;

    float y[8];
    #pragma unroll
    for (int q = 0; q < 8; ++q) y[q] = 0.f;

    // per-lane constants for cols hi*8..hi*8+7:
    // z = acc + med3(le+nx,1,2)*w4c ; acc = MFMA(A',y) + MFMA(N,nx) + c0p
    float c0p[8], w4c[8];
    {
        float av[8] = {0, 0, 0, 0, 0, 0, 0, 0};
        if (active) {
            float4 a0 = *reinterpret_cast<const float4*>(&atom[((size_t)b * TT + t0) * KK + hi * 8]);
            float4 a1 = *reinterpret_cast<const float4*>(&atom[((size_t)b * TT + t0) * KK + hi * 8 + 4]);
            av[0] = a0.x; av[1] = a0.y; av[2] = a0.z; av[3] = a0.w;
            av[4] = a1.x; av[5] = a1.y; av[6] = a1.z; av[7] = a1.w;
        }
        #pragma unroll
        for (int q = 0; q < 8; ++q) {
            int j = hi * 8 + q;
            float w1 = wop[1 * KK + j];
            float w2 = wop[2 * KK + j];
            float w4 = wop[4 * KK + j];
            c0p[q] = av[q] + w1 - w2 - w4;
            w4c[q] = 0.99f * w4;
        }
    }

    // A fragments: A'[k][col] = rw[k][col]*(w2+w4)[col] + (k==col+1 ? d1p[col] : 0)
    // N fragments: N[k][col]  = (k==col)*0.01*w4[col] + (k==col+1)*w3[col]
    // col0(m) = (m>>2)*8 + (m&3); af1/nf1 use col0+4.
    short8 af0, af1, nf0, nf1;
    {
        int col0 = ((lr >> 2) << 3) | (lr & 3);
        int col1 = col0 + 4;
        float w1a = wop[1 * KK + col0], w2a = wop[2 * KK + col0];
        float w3a = wop[3 * KK + col0], w4a = wop[4 * KK + col0];
        float w1b = wop[1 * KK + col1], w2b = wop[2 * KK + col1];
        float w3b = wop[3 * KK + col1], w4b = wop[4 * KK + col1];
        float sa = w2a + w4a, sb = w2b + w4b;
        float da = (w2a - w1a) + 0.01f * w4a;
        float db = (w2b - w1b) + 0.01f * w4b;
        #pragma unroll
        for (int q = 0; q < 8; ++q) {
            int k = hi * 8 + q;
            float a0 = rw[k * KK + col0] * sa + ((k == col0 + 1) ? da : 0.f);
            float a1 = rw[k * KK + col1] * sb + ((k == col1 + 1) ? db : 0.f);
            af0[q] = (short)f2bf(a0);
            af1[q] = (short)f2bf(a1);
            float n0 = (k == col0) ? 0.01f * w4a : ((k == col0 + 1) ? w3a : 0.f);
            float n1 = (k == col1) ? 0.01f * w4b : ((k == col1 + 1) ? w3b : 0.f);
            nf0[q] = (short)f2bf(n0);
            nf1[q] = (short)f2bf(n1);
        }
    }

    int pidx = ((lane + 16) & 63) << 2;   // bpermute byte addr for lane+16
    __syncthreads();

    for (int p = 0; p < NPHASE; ++p) {
        for (int s = 0; s < PH; ++s) {
            int cur = s & 1;
            if (active) {
                // row r+1 via DPP; tile-boundary row via broadcast LDS read
                float nx[8];
                #pragma unroll
                for (int q = 0; q < 8; ++q) nx[q] = dpp_shl1(y[q]);
                float lbr = __int_as_float(__builtin_amdgcn_ds_bpermute(pidx, __float_as_int(y[0])));
                float4 n0 = *reinterpret_cast<const float4*>(&brow[cur][rt + 1][hi * 8]);
                float4 n1 = *reinterpret_cast<const float4*>(&brow[cur][rt + 1][hi * 8 + 4]);
                nx[0] = l15 ? n0.x : nx[0];  nx[1] = l15 ? n0.y : nx[1];
                nx[2] = l15 ? n0.z : nx[2];  nx[3] = l15 ? n0.w : nx[3];
                nx[4] = l15 ? n1.x : nx[4];  nx[5] = l15 ? n1.y : nx[5];
                nx[6] = l15 ? n1.z : nx[6];  nx[7] = l15 ? n1.w : nx[7];
                float lb = h3 ? 0.f : lbr;

                // pack own row + next row to bf16 fragments
                unsigned bw0, bw1, bw2, bw3, nw0, nw1, nw2, nw3;
                asm("v_cvt_pk_bf16_f32 %0, %1, %2" : "=v"(bw0) : "v"(y[0]), "v"(y[1]));
                asm("v_cvt_pk_bf16_f32 %0, %1, %2" : "=v"(bw1) : "v"(y[2]), "v"(y[3]));
                asm("v_cvt_pk_bf16_f32 %0, %1, %2" : "=v"(bw2) : "v"(y[4]), "v"(y[5]));
                asm("v_cvt_pk_bf16_f32 %0, %1, %2" : "=v"(bw3) : "v"(y[6]), "v"(y[7]));
                asm("v_cvt_pk_bf16_f32 %0, %1, %2" : "=v"(nw0) : "v"(nx[0]), "v"(nx[1]));
                asm("v_cvt_pk_bf16_f32 %0, %1, %2" : "=v"(nw1) : "v"(nx[2]), "v"(nx[3]));
                asm("v_cvt_pk_bf16_f32 %0, %1, %2" : "=v"(nw2) : "v"(nx[4]), "v"(nx[5]));
                asm("v_cvt_pk_bf16_f32 %0, %1, %2" : "=v"(nw3) : "v"(nx[6]), "v"(nx[7]));
                union { unsigned u[4]; short8 v; } bu, nu;
                bu.u[0] = bw0; bu.u[1] = bw1; bu.u[2] = bw2; bu.u[3] = bw3;
                nu.u[0] = nw0; nu.u[1] = nw1; nu.u[2] = nw2; nu.u[3] = nw3;

                floatx4 acc0 = __builtin_amdgcn_mfma_f32_16x16x32_bf16(
                    af0, bu.v, (floatx4){c0p[0], c0p[1], c0p[2], c0p[3]}, 0, 0, 0);
                floatx4 acc1 = __builtin_amdgcn_mfma_f32_16x16x32_bf16(
                    af1, bu.v, (floatx4){c0p[4], c0p[5], c0p[6], c0p[7]}, 0, 0, 0);
                acc0 = __builtin_amdgcn_mfma_f32_16x16x32_bf16(nf0, nu.v, acc0, 0, 0, 0);
                acc1 = __builtin_amdgcn_mfma_f32_16x16x32_bf16(nf1, nu.v, acc1, 0, 0, 0);

                #pragma unroll
                for (int q = 0; q < 8; ++q) {
                    float accq = (q < 4) ? acc0[q] : acc1[q - 4];
                    float le = (q < 7) ? y[q + 1] : lb;
                    float sm = le + nx[q];
                    float t  = __builtin_amdgcn_fmed3f(sm, 1.f, 2.f);
                    float z  = fmaf(t, w4c[q], accq);
                    y[q] = myrelu(z);
                }

                // branchless boundary-row publish (lr==0 lanes hit brow, rest hit dummy)
                float* wp = (lr == 0) ? &brow[cur ^ 1][rt][hi * 8] : &dummy[lane][0];
                *reinterpret_cast<float4*>(wp)     = make_float4(y[0], y[1], y[2], y[3]);
                *reinterpret_cast<float4*>(wp + 4) = make_float4(y[4], y[5], y[6], y[7]);
            }
            __syncthreads();
        }
        if (p == NPHASE - 1) break;

        // ---- phase boundary: publish rows 0..31 (plain stores + fence + flag) ----
        if (rt < CH / 16 && c > 0) {
            float* gp = gs + (size_t)t0 * KK + hi * 8;
            *reinterpret_cast<float4*>(gp)     = make_float4(y[0], y[1], y[2], y[3]);
            *reinterpret_cast<float4*>(gp + 4) = make_float4(y[4], y[5], y[6], y[7]);
        }
        __syncthreads();   // vmcnt drained per-wave before barrier
        if (tid == 0) {
            if (c > 0) {
                __threadfence();   // agent-scope: wbl2 ensures stores visible at L3
                __hip_atomic_store(&flags[b * BPB + c], p + 1,
                                   __ATOMIC_RELEASE, __HIP_MEMORY_SCOPE_AGENT);
            }
            if (c < BPB - 1) {
                while (__hip_atomic_load(&flags[b * BPB + c + 1],
                                         __ATOMIC_ACQUIRE, __HIP_MEMORY_SCOPE_AGENT) < p + 1)
                    __builtin_amdgcn_s_sleep(2);
            }
        }
        __syncthreads();
        if (active && rt >= CH / 16) {      // halo waves 2,3 reload fresh rows
            unsigned long long* gp =
                reinterpret_cast<unsigned long long*>(gs + (size_t)t0 * KK + hi * 8);
            union { float f[8]; unsigned long long u[4]; } pk;
            #pragma unroll
            for (int w = 0; w < 4; ++w)
                pk.u[w] = __hip_atomic_load(&gp[w], __ATOMIC_RELAXED, __HIP_MEMORY_SCOPE_AGENT);
            #pragma unroll
            for (int q = 0; q < 8; ++q) y[q] = pk.f[q];
            if (lr == 0) {
                *reinterpret_cast<float4*>(&brow[0][rt][hi * 8])     = make_float4(y[0], y[1], y[2], y[3]);
                *reinterpret_cast<float4*>(&brow[0][rt][hi * 8 + 4]) = make_float4(y[4], y[5], y[6], y[7]);
            }
        }
        __syncthreads();
    }

    // epilogue: sigmoid + store (chunk waves 0..1 only)
    if (rt < CH / 16) {
        float* op = out + ((size_t)b * TT + t0) * KK + hi * 8;
        float o[8];
        #pragma unroll
        for (int q = 0; q < 8; ++q)
            o[q] = 1.f / (1.f + __expf(-5.f * (y[q] - 0.5f)));
        *reinterpret_cast<float4*>(&op[0]) = make_float4(o[0], o[1], o[2], o[3]);
        *reinterpret_cast<float4*>(&op[4]) = make_float4(o[4], o[5], o[6], o[7]);
    }
}

extern "C" void kernel_launch(void* const* d_in, const int* in_sizes, int n_in,
                              void* d_out, int out_size, void* d_ws, size_t ws_size,
                              hipStream_t stream) {
    const float* x       = (const float*)d_in[0];
    const float* w_right = (const float*)d_in[1];
    const float* w_op    = (const float*)d_in[2];
    float* ws  = (float*)d_ws;
    float* out = (float*)d_out;

    prep_kernel<<<1, 64, 0, stream>>>(w_right, w_op, ws);
    atomx_kernel<<<BB * TT / 8, 256, 0, stream>>>(x, ws);

    void* args[] = { (void*)&ws, (void*)&out };
    hipLaunchCooperativeKernel((void*)phase_all_kernel,
                               dim3(BB * BPB), dim3(256), args, 0, stream);
}

// Round 7
// 229.901 us; speedup vs baseline: 1.6207x; 1.6207x over previous
//
#include <hip/hip_runtime.h>
#include <math.h>

#define BB 64
#define TT 256
#define KK 32
#define VV 32
#define CH 64                    // output rows owned per block
#define PH 32                    // steps per block-phase (halo depth)
#define ROWS (CH + PH)           // 96 rows covered per block
#define BPB (TT / CH)            // 4 chunks per batch
#define OWN 12                   // rows owned per wave
#define HOLD 16                  // rows held per wave (4 halo)
#define NWAVE (ROWS / OWN)       // 8 waves
#define NTHR (NWAVE * 64)        // 512 threads
#define NWIN ((TT + KK) / 4)     // 72 windows of 4 steps = 288 steps

// workspace layout (floats)
#define RW_OFF    0                       // K*K
#define WOP_OFF   1024                    // 37*K
#define ATOM_OFF  2240                    // B*T*K
#define STATE_OFF (ATOM_OFF + BB*TT*KK)   // B*T*K (phase-boundary handoff)
#define FLAG_OFF  (STATE_OFF + BB*TT*KK)  // BB*BPB ints

typedef __attribute__((ext_vector_type(8))) short short8;
typedef __attribute__((ext_vector_type(4))) float floatx4;

__device__ __forceinline__ float myrelu(float z) {
    return fmaf(0.01f, z, 0.99f * __builtin_amdgcn_fmed3f(z, 0.f, 1.f));
}
__device__ __forceinline__ ushort f2bf(float f) {
    union { float f; unsigned int u; } v; v.f = f;
    unsigned int r = v.u + 0x7fffu + ((v.u >> 16) & 1u);
    return (ushort)(r >> 16);
}
__device__ __forceinline__ float dpp_shl1_f(float v) {
    // lane n <- lane n+1 within each 16-lane row; lane 15 of row -> 0
    return __int_as_float(__builtin_amdgcn_update_dpp(
        0, __float_as_int(v), 0x101, 0xF, 0xF, true));
}
__device__ __forceinline__ unsigned dpp_shl1_u(unsigned v) {
    return (unsigned)__builtin_amdgcn_update_dpp(
        0, (int)v, 0x101, 0xF, 0xF, true);
}

// --- softmaxes of w_op (32 x 37) and w_right (32 x 33) ---
__global__ void prep_kernel(const float* __restrict__ w_right,
                            const float* __restrict__ w_op,
                            float* __restrict__ ws) {
    int tid = threadIdx.x;
    float* rw  = ws + RW_OFF;   // rw[k*K + j] = softmax(w_right)[j][k]
    float* wop = ws + WOP_OFF;  // wop[i*K + k] = sm_op[k][i]
    if (tid < KK) {
        float v[37];
        float m = -1e30f;
        #pragma unroll
        for (int i = 0; i < 37; ++i) { v[i] = w_op[tid * 37 + i]; m = fmaxf(m, v[i]); }
        float s = 0.f;
        #pragma unroll
        for (int i = 0; i < 37; ++i) { v[i] = expf(v[i] - m); s += v[i]; }
        float inv = 1.f / s;
        #pragma unroll
        for (int i = 0; i < 37; ++i) wop[i * KK + tid] = v[i] * inv;
    } else if (tid < 2 * KK) {
        int r = tid - KK;
        float v[KK + 1];
        float m = -1e30f;
        #pragma unroll
        for (int i = 0; i <= KK; ++i) { v[i] = w_right[r * (KK + 1) + i]; m = fmaxf(m, v[i]); }
        float s = 0.f;
        #pragma unroll
        for (int i = 0; i <= KK; ++i) { v[i] = expf(v[i] - m); s += v[i]; }
        float inv = 1.f / s;
        #pragma unroll
        for (int c = 0; c < KK; ++c) rw[c * KK + r] = v[c] * inv;
    }
}

// --- atom_x = x @ atom_w ; zero the handshake flags ---
__global__ void atomx_kernel(const float* __restrict__ x, float* __restrict__ ws) {
    const float* aw = ws + WOP_OFF + 5 * KK;
    float* atom = ws + ATOM_OFF;
    int tid = threadIdx.x;
    if (blockIdx.x == 0 && tid < BB * BPB) ((int*)(ws + FLAG_OFF))[tid] = 0;
    int k  = tid & (KK - 1);
    int bt = blockIdx.x * 8 + (tid >> 5);
    const float* xrow = x + bt * VV;
    float acc = 0.f;
    #pragma unroll
    for (int v = 0; v < VV; ++v) acc = fmaf(xrow[v], aw[v * KK + k], acc);
    atom[bt * KK + k] = acc;
}

// --- all 288 steps; waves independent within 4-step windows ---
__global__ __launch_bounds__(NTHR, 1)
void phase_all_kernel(float* __restrict__ ws, float* __restrict__ out) {
    __shared__ float Xe[2][100][36];   // exchange buffer, dbuf (~28.1 KB)

    const float* rw   = ws + RW_OFF;
    const float* wop  = ws + WOP_OFF;
    const float* atom = ws + ATOM_OFF;
    float*      state = ws + STATE_OFF;
    int*        flags = (int*)(ws + FLAG_OFF);

    int tid  = threadIdx.x;
    int lane = tid & 63;
    int w    = tid >> 6;          // wave 0..7
    int lr   = lane & 15;
    int hi   = lane >> 4;
    int b  = blockIdx.x / BPB;
    int c  = blockIdx.x % BPB;
    int lo = c * CH;
    int lrow = w * OWN + lr;      // local row held by this lane (0..99)
    int t0   = lo + lrow;         // global row
    bool active   = (lo + w * OWN) < TT;            // wave has a real owned row
    bool straddle = active && (lo + w * OWN + HOLD - 1 >= TT);
    bool tok      = (t0 < TT);
    bool h3       = (hi == 3);

    // zero exchange buffers (incl. pad rows 96..99, never rewritten)
    for (int i = tid; i < 2 * 100 * 36; i += NTHR) (&Xe[0][0][0])[i] = 0.f;

    float* gs = state + (size_t)b * TT * KK;

    float y[8];
    #pragma unroll
    for (int q = 0; q < 8; ++q) y[q] = 0.f;

    // per-lane constants for cols hi*8..hi*8+7
    float c0p[8], w4c[8];
    {
        float av[8] = {0, 0, 0, 0, 0, 0, 0, 0};
        if (tok) {
            float4 a0 = *reinterpret_cast<const float4*>(&atom[((size_t)b * TT + t0) * KK + hi * 8]);
            float4 a1 = *reinterpret_cast<const float4*>(&atom[((size_t)b * TT + t0) * KK + hi * 8 + 4]);
            av[0] = a0.x; av[1] = a0.y; av[2] = a0.z; av[3] = a0.w;
            av[4] = a1.x; av[5] = a1.y; av[6] = a1.z; av[7] = a1.w;
        }
        #pragma unroll
        for (int q = 0; q < 8; ++q) {
            int j = hi * 8 + q;
            float w1 = wop[1 * KK + j];
            float w2 = wop[2 * KK + j];
            float w4 = wop[4 * KK + j];
            c0p[q] = av[q] + w1 - w2 - w4;
            w4c[q] = 0.99f * w4;
        }
    }

    // A' and N fragments (same folds as r6, verified):
    // A'[k][col] = rw[k][col]*(w2+w4) + (k==col+1)*d1p ; N[k][col]=(k==col)*0.01w4+(k==col+1)*w3
    short8 af0, af1, nf0, nf1;
    {
        int col0 = ((lr >> 2) << 3) | (lr & 3);
        int col1 = col0 + 4;
        float w1a = wop[1 * KK + col0], w2a = wop[2 * KK + col0];
        float w3a = wop[3 * KK + col0], w4a = wop[4 * KK + col0];
        float w1b = wop[1 * KK + col1], w2b = wop[2 * KK + col1];
        float w3b = wop[3 * KK + col1], w4b = wop[4 * KK + col1];
        float sa = w2a + w4a, sb = w2b + w4b;
        float da = (w2a - w1a) + 0.01f * w4a;
        float db = (w2b - w1b) + 0.01f * w4b;
        #pragma unroll
        for (int q = 0; q < 8; ++q) {
            int k = hi * 8 + q;
            af0[q] = (short)f2bf(rw[k * KK + col0] * sa + ((k == col0 + 1) ? da : 0.f));
            af1[q] = (short)f2bf(rw[k * KK + col1] * sb + ((k == col1 + 1) ? db : 0.f));
            nf0[q] = (short)f2bf((k == col0) ? 0.01f * w4a : ((k == col0 + 1) ? w3a : 0.f));
            nf1[q] = (short)f2bf((k == col1) ? 0.01f * w4b : ((k == col1 + 1) ? w3b : 0.f));
        }
    }

    int pidx = ((lane + 16) & 63) << 2;   // bpermute addr for lane+16
    __syncthreads();

    for (int e = 0; e < NWIN; ++e) {
        if (active) {
            #pragma unroll
            for (int s = 0; s < 4; ++s) {
                // neighbor row (lrow+1) via DPP row_shl:1 (lr==15 -> 0, erodes halo)
                float nx[8];
                #pragma unroll
                for (int q = 0; q < 8; ++q) nx[q] = dpp_shl1_f(y[q]);
                float lbr = __int_as_float(__builtin_amdgcn_ds_bpermute(pidx, __float_as_int(y[0])));
                float lb  = h3 ? 0.f : lbr;     // col hi*8+8 of own row

                unsigned bw0, bw1, bw2, bw3;
                asm("v_cvt_pk_bf16_f32 %0, %1, %2" : "=v"(bw0) : "v"(y[0]), "v"(y[1]));
                asm("v_cvt_pk_bf16_f32 %0, %1, %2" : "=v"(bw1) : "v"(y[2]), "v"(y[3]));
                asm("v_cvt_pk_bf16_f32 %0, %1, %2" : "=v"(bw2) : "v"(y[4]), "v"(y[5]));
                asm("v_cvt_pk_bf16_f32 %0, %1, %2" : "=v"(bw3) : "v"(y[6]), "v"(y[7]));
                union { unsigned u[4]; short8 v; } bu, nu;
                bu.u[0] = bw0; bu.u[1] = bw1; bu.u[2] = bw2; bu.u[3] = bw3;
                nu.u[0] = dpp_shl1_u(bw0); nu.u[1] = dpp_shl1_u(bw1);
                nu.u[2] = dpp_shl1_u(bw2); nu.u[3] = dpp_shl1_u(bw3);

                floatx4 acc0 = __builtin_amdgcn_mfma_f32_16x16x32_bf16(
                    af0, bu.v, (floatx4){c0p[0], c0p[1], c0p[2], c0p[3]}, 0, 0, 0);
                floatx4 acc1 = __builtin_amdgcn_mfma_f32_16x16x32_bf16(
                    af1, bu.v, (floatx4){c0p[4], c0p[5], c0p[6], c0p[7]}, 0, 0, 0);
                acc0 = __builtin_amdgcn_mfma_f32_16x16x32_bf16(nf0, nu.v, acc0, 0, 0, 0);
                acc1 = __builtin_amdgcn_mfma_f32_16x16x32_bf16(nf1, nu.v, acc1, 0, 0, 0);

                #pragma unroll
                for (int q = 0; q < 8; ++q) {
                    float accq = (q < 4) ? acc0[q] : acc1[q - 4];
                    float le = (q < 7) ? y[q + 1] : lb;
                    float sm = le + nx[q];
                    float t  = __builtin_amdgcn_fmed3f(sm, 1.f, 2.f);
                    float z  = fmaf(t, w4c[q], accq);
                    y[q] = myrelu(z);
                }
                if (straddle) {
                    #pragma unroll
                    for (int q = 0; q < 8; ++q) y[q] = tok ? y[q] : 0.f;
                }
            }
        }
        if (e == NWIN - 1) break;

        // ---- every 8th window: cross-block phase boundary (32 steps) ----
        if ((e & 7) == 7) {
            int vv = (e >> 3) + 1;
            if (c > 0 && lr < OWN && lrow < PH) {   // publish owned rows 0..31
                float* gp = gs + (size_t)t0 * KK + hi * 8;
                *reinterpret_cast<float4*>(gp)     = make_float4(y[0], y[1], y[2], y[3]);
                *reinterpret_cast<float4*>(gp + 4) = make_float4(y[4], y[5], y[6], y[7]);
            }
            __syncthreads();
            if (tid == 0) {
                if (c > 0) {
                    __threadfence();
                    __hip_atomic_store(&flags[b * BPB + c], vv,
                                       __ATOMIC_RELEASE, __HIP_MEMORY_SCOPE_AGENT);
                }
                if (c < BPB - 1) {
                    while (__hip_atomic_load(&flags[b * BPB + c + 1],
                                             __ATOMIC_ACQUIRE, __HIP_MEMORY_SCOPE_AGENT) < vv)
                        __builtin_amdgcn_s_sleep(2);
                }
            }
            __syncthreads();
            if (lr < OWN && lrow >= CH && tok) {    // reload owned halo-region rows
                unsigned long long* gp =
                    reinterpret_cast<unsigned long long*>(gs + (size_t)t0 * KK + hi * 8);
                union { float f[8]; unsigned long long u[4]; } pk;
                #pragma unroll
                for (int u = 0; u < 4; ++u)
                    pk.u[u] = __hip_atomic_load(&gp[u], __ATOMIC_RELAXED, __HIP_MEMORY_SCOPE_AGENT);
                #pragma unroll
                for (int q = 0; q < 8; ++q) y[q] = pk.f[q];
            }
        }

        // ---- wave-halo exchange via LDS (dbuf, one barrier) ----
        int par = e & 1;
        if (lr < OWN) {
            float* wp = &Xe[par][lrow][hi * 8];
            *reinterpret_cast<float4*>(wp)     = make_float4(y[0], y[1], y[2], y[3]);
            *reinterpret_cast<float4*>(wp + 4) = make_float4(y[4], y[5], y[6], y[7]);
        }
        __syncthreads();
        if (lr >= OWN) {
            const float* rp = &Xe[par][lrow][hi * 8];
            float4 v0 = *reinterpret_cast<const float4*>(rp);
            float4 v1 = *reinterpret_cast<const float4*>(rp + 4);
            y[0] = v0.x; y[1] = v0.y; y[2] = v0.z; y[3] = v0.w;
            y[4] = v1.x; y[5] = v1.y; y[6] = v1.z; y[7] = v1.w;
        }
    }

    // epilogue: sigmoid + store owned chunk rows
    if (lr < OWN && lrow < CH) {
        float* op = out + ((size_t)b * TT + t0) * KK + hi * 8;
        float o[8];
        #pragma unroll
        for (int q = 0; q < 8; ++q)
            o[q] = 1.f / (1.f + __expf(-5.f * (y[q] - 0.5f)));
        *reinterpret_cast<float4*>(&op[0]) = make_float4(o[0], o[1], o[2], o[3]);
        *reinterpret_cast<float4*>(&op[4]) = make_float4(o[4], o[5], o[6], o[7]);
    }
}

extern "C" void kernel_launch(void* const* d_in, const int* in_sizes, int n_in,
                              void* d_out, int out_size, void* d_ws, size_t ws_size,
                              hipStream_t stream) {
    const float* x       = (const float*)d_in[0];
    const float* w_right = (const float*)d_in[1];
    const float* w_op    = (const float*)d_in[2];
    float* ws  = (float*)d_ws;
    float* out = (float*)d_out;

    prep_kernel<<<1, 64, 0, stream>>>(w_right, w_op, ws);
    atomx_kernel<<<BB * TT / 8, 256, 0, stream>>>(x, ws);

    void* args[] = { (void*)&ws, (void*)&out };
    hipLaunchCooperativeKernel((void*)phase_all_kernel,
                               dim3(BB * BPB), dim3(NTHR), args, 0, stream);
}

// Round 8
// 225.598 us; speedup vs baseline: 1.6517x; 1.0191x over previous
//
#include <hip/hip_runtime.h>
#include <math.h>

#define BB 64
#define TT 256
#define KK 32
#define VV 32
#define CH 64                    // output rows owned per block
#define PH 32                    // steps per block-phase (halo depth)
#define ROWS (CH + PH)           // 96 rows covered per block
#define BPB (TT / CH)            // 4 chunks per batch
#define OWN 12                   // rows owned per wave
#define HOLD 16                  // rows held per wave (4 halo)
#define NWAVE (ROWS / OWN)       // 8 waves
#define NTHR (NWAVE * 64)        // 512 threads
#define NWIN ((TT + KK) / 4)     // 72 windows of 4 steps = 288 steps

// workspace layout (floats)
#define RW_OFF    0                       // K*K
#define WOP_OFF   1024                    // 37*K
#define ATOM_OFF  2240                    // B*T*K
#define STATE_OFF (ATOM_OFF + BB*TT*KK)   // B*T*K (phase-boundary handoff)
#define FLAG_OFF  (STATE_OFF + BB*TT*KK)  // BB*BPB ints

typedef __attribute__((ext_vector_type(8))) short short8;
typedef __attribute__((ext_vector_type(4))) float floatx4;
typedef __attribute__((ext_vector_type(4))) int intx4;

__device__ __forceinline__ float myrelu(float z) {
    return fmaf(0.01f, z, 0.99f * __builtin_amdgcn_fmed3f(z, 0.f, 1.f));
}
__device__ __forceinline__ ushort f2bf(float f) {
    union { float f; unsigned int u; } v; v.f = f;
    unsigned int r = v.u + 0x7fffu + ((v.u >> 16) & 1u);
    return (ushort)(r >> 16);
}
__device__ __forceinline__ float dpp_shl1_f(float v) {
    // lane n <- lane n+1 within each 16-lane row; lane 15 of row -> 0
    return __int_as_float(__builtin_amdgcn_update_dpp(
        0, __float_as_int(v), 0x101, 0xF, 0xF, true));
}
__device__ __forceinline__ unsigned dpp_shl1_u(unsigned v) {
    return (unsigned)__builtin_amdgcn_update_dpp(
        0, (int)v, 0x101, 0xF, 0xF, true);
}

// --- softmaxes of w_op (32 x 37) and w_right (32 x 33) ---
__global__ void prep_kernel(const float* __restrict__ w_right,
                            const float* __restrict__ w_op,
                            float* __restrict__ ws) {
    int tid = threadIdx.x;
    float* rw  = ws + RW_OFF;   // rw[k*K + j] = softmax(w_right)[j][k]
    float* wop = ws + WOP_OFF;  // wop[i*K + k] = sm_op[k][i]
    if (tid < KK) {
        float v[37];
        float m = -1e30f;
        #pragma unroll
        for (int i = 0; i < 37; ++i) { v[i] = w_op[tid * 37 + i]; m = fmaxf(m, v[i]); }
        float s = 0.f;
        #pragma unroll
        for (int i = 0; i < 37; ++i) { v[i] = expf(v[i] - m); s += v[i]; }
        float inv = 1.f / s;
        #pragma unroll
        for (int i = 0; i < 37; ++i) wop[i * KK + tid] = v[i] * inv;
    } else if (tid < 2 * KK) {
        int r = tid - KK;
        float v[KK + 1];
        float m = -1e30f;
        #pragma unroll
        for (int i = 0; i <= KK; ++i) { v[i] = w_right[r * (KK + 1) + i]; m = fmaxf(m, v[i]); }
        float s = 0.f;
        #pragma unroll
        for (int i = 0; i <= KK; ++i) { v[i] = expf(v[i] - m); s += v[i]; }
        float inv = 1.f / s;
        #pragma unroll
        for (int c = 0; c < KK; ++c) rw[c * KK + r] = v[c] * inv;
    }
}

// --- atom_x = x @ atom_w ; zero the handshake flags ---
__global__ void atomx_kernel(const float* __restrict__ x, float* __restrict__ ws) {
    const float* aw = ws + WOP_OFF + 5 * KK;
    float* atom = ws + ATOM_OFF;
    int tid = threadIdx.x;
    if (blockIdx.x == 0 && tid < BB * BPB) ((int*)(ws + FLAG_OFF))[tid] = 0;
    int k  = tid & (KK - 1);
    int bt = blockIdx.x * 8 + (tid >> 5);
    const float* xrow = x + bt * VV;
    float acc = 0.f;
    #pragma unroll
    for (int v = 0; v < VV; ++v) acc = fmaf(xrow[v], aw[v * KK + k], acc);
    atom[bt * KK + k] = acc;
}

// --- all 288 steps; waves independent within 4-step windows; fully scalar regs ---
__global__ __launch_bounds__(NTHR, 1)
void phase_all_kernel(float* __restrict__ ws, float* __restrict__ out) {
    __shared__ float Xe[2][100][36];   // exchange buffer, dbuf (~28.8 KB)

    const float* rw   = ws + RW_OFF;
    const float* wop  = ws + WOP_OFF;
    const float* atom = ws + ATOM_OFF;
    float*      state = ws + STATE_OFF;
    int*        flags = (int*)(ws + FLAG_OFF);

    int tid  = threadIdx.x;
    int lane = tid & 63;
    int w    = tid >> 6;          // wave 0..7
    int lr   = lane & 15;
    int hi   = lane >> 4;
    int b  = blockIdx.x / BPB;
    int c  = blockIdx.x % BPB;
    int lo = c * CH;
    int lrow = w * OWN + lr;      // local row held by this lane (0..99)
    int t0   = lo + lrow;         // global row
    bool active   = (lo + w * OWN) < TT;            // wave has a real owned row
    bool straddle = active && (lo + w * OWN + HOLD - 1 >= TT);
    bool tok      = (t0 < TT);
    bool h3       = (hi == 3);

    for (int i = tid; i < 2 * 100 * 36; i += NTHR) (&Xe[0][0][0])[i] = 0.f;

    float* gs = state + (size_t)b * TT * KK;

    float y0 = 0.f, y1 = 0.f, y2 = 0.f, y3 = 0.f;
    float y4 = 0.f, y5 = 0.f, y6 = 0.f, y7 = 0.f;

    // per-lane constants for cols hi*8..hi*8+7 (named scalars / vectors only)
    floatx4 c0a, c0b;
    float w4c0, w4c1, w4c2, w4c3, w4c4, w4c5, w4c6, w4c7;
    {
        float4 a0 = make_float4(0, 0, 0, 0), a1 = make_float4(0, 0, 0, 0);
        if (tok) {
            a0 = *reinterpret_cast<const float4*>(&atom[((size_t)b * TT + t0) * KK + hi * 8]);
            a1 = *reinterpret_cast<const float4*>(&atom[((size_t)b * TT + t0) * KK + hi * 8 + 4]);
        }
        const float* w1p = wop + 1 * KK + hi * 8;
        const float* w2p = wop + 2 * KK + hi * 8;
        const float* w4p = wop + 4 * KK + hi * 8;
        c0a = (floatx4){a0.x + w1p[0] - w2p[0] - w4p[0],
                        a0.y + w1p[1] - w2p[1] - w4p[1],
                        a0.z + w1p[2] - w2p[2] - w4p[2],
                        a0.w + w1p[3] - w2p[3] - w4p[3]};
        c0b = (floatx4){a1.x + w1p[4] - w2p[4] - w4p[4],
                        a1.y + w1p[5] - w2p[5] - w4p[5],
                        a1.z + w1p[6] - w2p[6] - w4p[6],
                        a1.w + w1p[7] - w2p[7] - w4p[7]};
        w4c0 = 0.99f * w4p[0]; w4c1 = 0.99f * w4p[1];
        w4c2 = 0.99f * w4p[2]; w4c3 = 0.99f * w4p[3];
        w4c4 = 0.99f * w4p[4]; w4c5 = 0.99f * w4p[5];
        w4c6 = 0.99f * w4p[6]; w4c7 = 0.99f * w4p[7];
    }

    // A' and N fragments (same folds as r6/r7, verified):
    // A'[k][col] = rw[k][col]*(w2+w4) + (k==col+1)*d1p ; N[k][col]=(k==col)*0.01w4+(k==col+1)*w3
    short8 af0, af1, nf0, nf1;
    {
        int col0 = ((lr >> 2) << 3) | (lr & 3);
        int col1 = col0 + 4;
        float w1a = wop[1 * KK + col0], w2a = wop[2 * KK + col0];
        float w3a = wop[3 * KK + col0], w4a = wop[4 * KK + col0];
        float w1b = wop[1 * KK + col1], w2b = wop[2 * KK + col1];
        float w3b = wop[3 * KK + col1], w4b = wop[4 * KK + col1];
        float sa = w2a + w4a, sb = w2b + w4b;
        float da = (w2a - w1a) + 0.01f * w4a;
        float db = (w2b - w1b) + 0.01f * w4b;
        const float* rwc0 = rw + col0;
        const float* rwc1 = rw + col1;
        int k0 = hi * 8;
        af0 = (short8){
            (short)f2bf(rwc0[(k0+0)*KK] * sa + ((k0+0 == col0+1) ? da : 0.f)),
            (short)f2bf(rwc0[(k0+1)*KK] * sa + ((k0+1 == col0+1) ? da : 0.f)),
            (short)f2bf(rwc0[(k0+2)*KK] * sa + ((k0+2 == col0+1) ? da : 0.f)),
            (short)f2bf(rwc0[(k0+3)*KK] * sa + ((k0+3 == col0+1) ? da : 0.f)),
            (short)f2bf(rwc0[(k0+4)*KK] * sa + ((k0+4 == col0+1) ? da : 0.f)),
            (short)f2bf(rwc0[(k0+5)*KK] * sa + ((k0+5 == col0+1) ? da : 0.f)),
            (short)f2bf(rwc0[(k0+6)*KK] * sa + ((k0+6 == col0+1) ? da : 0.f)),
            (short)f2bf(rwc0[(k0+7)*KK] * sa + ((k0+7 == col0+1) ? da : 0.f))};
        af1 = (short8){
            (short)f2bf(rwc1[(k0+0)*KK] * sb + ((k0+0 == col1+1) ? db : 0.f)),
            (short)f2bf(rwc1[(k0+1)*KK] * sb + ((k0+1 == col1+1) ? db : 0.f)),
            (short)f2bf(rwc1[(k0+2)*KK] * sb + ((k0+2 == col1+1) ? db : 0.f)),
            (short)f2bf(rwc1[(k0+3)*KK] * sb + ((k0+3 == col1+1) ? db : 0.f)),
            (short)f2bf(rwc1[(k0+4)*KK] * sb + ((k0+4 == col1+1) ? db : 0.f)),
            (short)f2bf(rwc1[(k0+5)*KK] * sb + ((k0+5 == col1+1) ? db : 0.f)),
            (short)f2bf(rwc1[(k0+6)*KK] * sb + ((k0+6 == col1+1) ? db : 0.f)),
            (short)f2bf(rwc1[(k0+7)*KK] * sb + ((k0+7 == col1+1) ? db : 0.f))};
        nf0 = (short8){
            (short)f2bf((k0+0 == col0) ? 0.01f*w4a : ((k0+0 == col0+1) ? w3a : 0.f)),
            (short)f2bf((k0+1 == col0) ? 0.01f*w4a : ((k0+1 == col0+1) ? w3a : 0.f)),
            (short)f2bf((k0+2 == col0) ? 0.01f*w4a : ((k0+2 == col0+1) ? w3a : 0.f)),
            (short)f2bf((k0+3 == col0) ? 0.01f*w4a : ((k0+3 == col0+1) ? w3a : 0.f)),
            (short)f2bf((k0+4 == col0) ? 0.01f*w4a : ((k0+4 == col0+1) ? w3a : 0.f)),
            (short)f2bf((k0+5 == col0) ? 0.01f*w4a : ((k0+5 == col0+1) ? w3a : 0.f)),
            (short)f2bf((k0+6 == col0) ? 0.01f*w4a : ((k0+6 == col0+1) ? w3a : 0.f)),
            (short)f2bf((k0+7 == col0) ? 0.01f*w4a : ((k0+7 == col0+1) ? w3a : 0.f))};
        nf1 = (short8){
            (short)f2bf((k0+0 == col1) ? 0.01f*w4b : ((k0+0 == col1+1) ? w3b : 0.f)),
            (short)f2bf((k0+1 == col1) ? 0.01f*w4b : ((k0+1 == col1+1) ? w3b : 0.f)),
            (short)f2bf((k0+2 == col1) ? 0.01f*w4b : ((k0+2 == col1+1) ? w3b : 0.f)),
            (short)f2bf((k0+3 == col1) ? 0.01f*w4b : ((k0+3 == col1+1) ? w3b : 0.f)),
            (short)f2bf((k0+4 == col1) ? 0.01f*w4b : ((k0+4 == col1+1) ? w3b : 0.f)),
            (short)f2bf((k0+5 == col1) ? 0.01f*w4b : ((k0+5 == col1+1) ? w3b : 0.f)),
            (short)f2bf((k0+6 == col1) ? 0.01f*w4b : ((k0+6 == col1+1) ? w3b : 0.f)),
            (short)f2bf((k0+7 == col1) ? 0.01f*w4b : ((k0+7 == col1+1) ? w3b : 0.f))};
    }

    int pidx = ((lane + 16) & 63) << 2;   // bpermute addr for lane+16
    __syncthreads();

    for (int e = 0; e < NWIN; ++e) {
        if (active) {
            #pragma unroll
            for (int s = 0; s < 4; ++s) {
                float nx0 = dpp_shl1_f(y0), nx1 = dpp_shl1_f(y1);
                float nx2 = dpp_shl1_f(y2), nx3 = dpp_shl1_f(y3);
                float nx4 = dpp_shl1_f(y4), nx5 = dpp_shl1_f(y5);
                float nx6 = dpp_shl1_f(y6), nx7 = dpp_shl1_f(y7);
                float lbr = __int_as_float(__builtin_amdgcn_ds_bpermute(pidx, __float_as_int(y0)));
                float lb  = h3 ? 0.f : lbr;

                unsigned bw0, bw1, bw2, bw3;
                asm("v_cvt_pk_bf16_f32 %0, %1, %2" : "=v"(bw0) : "v"(y0), "v"(y1));
                asm("v_cvt_pk_bf16_f32 %0, %1, %2" : "=v"(bw1) : "v"(y2), "v"(y3));
                asm("v_cvt_pk_bf16_f32 %0, %1, %2" : "=v"(bw2) : "v"(y4), "v"(y5));
                asm("v_cvt_pk_bf16_f32 %0, %1, %2" : "=v"(bw3) : "v"(y6), "v"(y7));
                short8 bv = __builtin_bit_cast(short8,
                    (intx4){(int)bw0, (int)bw1, (int)bw2, (int)bw3});
                short8 nv = __builtin_bit_cast(short8,
                    (intx4){(int)dpp_shl1_u(bw0), (int)dpp_shl1_u(bw1),
                            (int)dpp_shl1_u(bw2), (int)dpp_shl1_u(bw3)});

                floatx4 acc0 = __builtin_amdgcn_mfma_f32_16x16x32_bf16(af0, bv, c0a, 0, 0, 0);
                floatx4 acc1 = __builtin_amdgcn_mfma_f32_16x16x32_bf16(af1, bv, c0b, 0, 0, 0);
                acc0 = __builtin_amdgcn_mfma_f32_16x16x32_bf16(nf0, nv, acc0, 0, 0, 0);
                acc1 = __builtin_amdgcn_mfma_f32_16x16x32_bf16(nf1, nv, acc1, 0, 0, 0);

                // ascending order: le = old y[q+1], not yet overwritten
                {
                    float sm = y1 + nx0, t = __builtin_amdgcn_fmed3f(sm, 1.f, 2.f);
                    y0 = myrelu(fmaf(t, w4c0, acc0[0]));
                }
                {
                    float sm = y2 + nx1, t = __builtin_amdgcn_fmed3f(sm, 1.f, 2.f);
                    y1 = myrelu(fmaf(t, w4c1, acc0[1]));
                }
                {
                    float sm = y3 + nx2, t = __builtin_amdgcn_fmed3f(sm, 1.f, 2.f);
                    y2 = myrelu(fmaf(t, w4c2, acc0[2]));
                }
                {
                    float sm = y4 + nx3, t = __builtin_amdgcn_fmed3f(sm, 1.f, 2.f);
                    y3 = myrelu(fmaf(t, w4c3, acc0[3]));
                }
                {
                    float sm = y5 + nx4, t = __builtin_amdgcn_fmed3f(sm, 1.f, 2.f);
                    y4 = myrelu(fmaf(t, w4c4, acc1[0]));
                }
                {
                    float sm = y6 + nx5, t = __builtin_amdgcn_fmed3f(sm, 1.f, 2.f);
                    y5 = myrelu(fmaf(t, w4c5, acc1[1]));
                }
                {
                    float sm = y7 + nx6, t = __builtin_amdgcn_fmed3f(sm, 1.f, 2.f);
                    y6 = myrelu(fmaf(t, w4c6, acc1[2]));
                }
                {
                    float sm = lb + nx7, t = __builtin_amdgcn_fmed3f(sm, 1.f, 2.f);
                    y7 = myrelu(fmaf(t, w4c7, acc1[3]));
                }
                if (straddle && !tok) {
                    y0 = y1 = y2 = y3 = y4 = y5 = y6 = y7 = 0.f;
                }
            }
        }
        if (e == NWIN - 1) break;

        // ---- every 8th window: cross-block phase boundary (32 steps) ----
        if ((e & 7) == 7) {
            int vv = (e >> 3) + 1;
            if (c > 0 && lr < OWN && lrow < PH) {   // publish owned rows 0..31
                float* gp = gs + (size_t)t0 * KK + hi * 8;
                *reinterpret_cast<float4*>(gp)     = make_float4(y0, y1, y2, y3);
                *reinterpret_cast<float4*>(gp + 4) = make_float4(y4, y5, y6, y7);
            }
            __syncthreads();
            if (tid == 0) {
                if (c > 0) {
                    __threadfence();
                    __hip_atomic_store(&flags[b * BPB + c], vv,
                                       __ATOMIC_RELEASE, __HIP_MEMORY_SCOPE_AGENT);
                }
                if (c < BPB - 1) {
                    while (__hip_atomic_load(&flags[b * BPB + c + 1],
                                             __ATOMIC_ACQUIRE, __HIP_MEMORY_SCOPE_AGENT) < vv)
                        __builtin_amdgcn_s_sleep(2);
                }
            }
            __syncthreads();
            if (lr < OWN && lrow >= CH && tok) {    // reload owned halo-region rows
                unsigned long long* gp =
                    reinterpret_cast<unsigned long long*>(gs + (size_t)t0 * KK + hi * 8);
                unsigned long long u0 = __hip_atomic_load(&gp[0], __ATOMIC_RELAXED, __HIP_MEMORY_SCOPE_AGENT);
                unsigned long long u1 = __hip_atomic_load(&gp[1], __ATOMIC_RELAXED, __HIP_MEMORY_SCOPE_AGENT);
                unsigned long long u2 = __hip_atomic_load(&gp[2], __ATOMIC_RELAXED, __HIP_MEMORY_SCOPE_AGENT);
                unsigned long long u3 = __hip_atomic_load(&gp[3], __ATOMIC_RELAXED, __HIP_MEMORY_SCOPE_AGENT);
                y0 = __uint_as_float((unsigned)u0); y1 = __uint_as_float((unsigned)(u0 >> 32));
                y2 = __uint_as_float((unsigned)u1); y3 = __uint_as_float((unsigned)(u1 >> 32));
                y4 = __uint_as_float((unsigned)u2); y5 = __uint_as_float((unsigned)(u2 >> 32));
                y6 = __uint_as_float((unsigned)u3); y7 = __uint_as_float((unsigned)(u3 >> 32));
            }
        }

        // ---- wave-halo exchange via LDS (dbuf, one barrier) ----
        int par = e & 1;
        if (lr < OWN) {
            float* wp = &Xe[par][lrow][hi * 8];
            *reinterpret_cast<float4*>(wp)     = make_float4(y0, y1, y2, y3);
            *reinterpret_cast<float4*>(wp + 4) = make_float4(y4, y5, y6, y7);
        }
        __syncthreads();
        if (lr >= OWN) {
            const float* rp = &Xe[par][lrow][hi * 8];
            float4 v0 = *reinterpret_cast<const float4*>(rp);
            float4 v1 = *reinterpret_cast<const float4*>(rp + 4);
            y0 = v0.x; y1 = v0.y; y2 = v0.z; y3 = v0.w;
            y4 = v1.x; y5 = v1.y; y6 = v1.z; y7 = v1.w;
        }
    }

    // epilogue: sigmoid + store owned chunk rows
    if (lr < OWN && lrow < CH) {
        float* op = out + ((size_t)b * TT + t0) * KK + hi * 8;
        float o0 = 1.f / (1.f + __expf(-5.f * (y0 - 0.5f)));
        float o1 = 1.f / (1.f + __expf(-5.f * (y1 - 0.5f)));
        float o2 = 1.f / (1.f + __expf(-5.f * (y2 - 0.5f)));
        float o3 = 1.f / (1.f + __expf(-5.f * (y3 - 0.5f)));
        float o4 = 1.f / (1.f + __expf(-5.f * (y4 - 0.5f)));
        float o5 = 1.f / (1.f + __expf(-5.f * (y5 - 0.5f)));
        float o6 = 1.f / (1.f + __expf(-5.f * (y6 - 0.5f)));
        float o7 = 1.f / (1.f + __expf(-5.f * (y7 - 0.5f)));
        *reinterpret_cast<float4*>(&op[0]) = make_float4(o0, o1, o2, o3);
        *reinterpret_cast<float4*>(&op[4]) = make_float4(o4, o5, o6, o7);
    }
}

extern "C" void kernel_launch(void* const* d_in, const int* in_sizes, int n_in,
                              void* d_out, int out_size, void* d_ws, size_t ws_size,
                              hipStream_t stream) {
    const float* x       = (const float*)d_in[0];
    const float* w_right = (const float*)d_in[1];
    const float* w_op    = (const float*)d_in[2];
    float* ws  = (float*)d_ws;
    float* out = (float*)d_out;

    prep_kernel<<<1, 64, 0, stream>>>(w_right, w_op, ws);
    atomx_kernel<<<BB * TT / 8, 256, 0, stream>>>(x, ws);

    void* args[] = { (void*)&ws, (void*)&out };
    hipLaunchCooperativeKernel((void*)phase_all_kernel,
                               dim3(BB * BPB), dim3(NTHR), args, 0, stream);
}